// Round 5
// baseline (368.311 us; speedup 1.0000x reference)
//
#include <hip/hip_runtime.h>

#define BATCH 16
#define LEN 1024
#define DIM_IN 256
#define PAST 16
#define OUTROWS (LEN - PAST)   /* 1008 */
#define NLAYERS 3
#define O_ELEMS ((size_t)BATCH * OUTROWS * 256)   /* 4,128,768 */

// One wave (64 lanes) per attention row. Computes the 2-entry softmax,
// writes the new out-row (ping-pong ws buffer) and the full 1024-float
// attn row (zeros except 2 entries) -> zero-fill fused here.
template<int D, int LAYER>
__global__ __launch_bounds__(256) void layer_kernel(const float* __restrict__ in,
                                                    float* __restrict__ out,
                                                    float* __restrict__ attn)
{
    const int w    = threadIdx.x >> 6;
    const int lane = threadIdx.x & 63;
    const int r    = blockIdx.x * 4 + w;
    const int b    = r >> 10;
    const int l    = r & 1023;

    const float4* rowL = (const float4*)(in + (size_t)(b * LEN + l) * DIM_IN);
    float4 x = rowL[lane];
    float4 y = make_float4(0.f, 0.f, 0.f, 0.f);
    if (l >= D) {
        const float4* rowP = (const float4*)(in + (size_t)(b * LEN + l - D) * DIM_IN);
        y = rowP[lane];
    }

    float dot0 = x.x * x.x + x.y * x.y + x.z * x.z + x.w * x.w;
    float dot1 = x.x * y.x + x.y * y.y + x.z * y.z + x.w * y.w;
    #pragma unroll
    for (int off = 32; off; off >>= 1) {
        dot0 += __shfl_xor(dot0, off, 64);
        dot1 += __shfl_xor(dot1, off, 64);
    }

    const float scale = 0.0625f;  // 1/sqrt(256)
    float p0 = 1.f, p1 = 0.f;
    if (l >= D) {
        float s0 = dot0 * scale, s1 = dot1 * scale;
        float m  = fmaxf(s0, s1);
        float e0 = expf(s0 - m), e1 = expf(s1 - m);
        float inv = 1.f / (e0 + e1);
        p0 = e0 * inv;
        p1 = e1 * inv;
    }

    // out_new = out + attn @ out  ( = (1+p0)*x + p1*y )
    float4* orow = (float4*)(out + (size_t)(b * LEN + l) * DIM_IN);
    const float a0 = 1.f + p0;
    float4 nv;
    nv.x = x.x * a0 + y.x * p1;
    nv.y = x.y * a0 + y.y * p1;
    nv.z = x.z * a0 + y.z * p1;
    nv.w = x.w * a0 + y.w * p1;
    orow[lane] = nv;

    // attn_stack[b, LAYER, l, :]: zeros except col l -> p0, col l-D -> p1
    float4* arow = (float4*)(attn + ((size_t)(b * NLAYERS + LAYER) * LEN + l) * (size_t)LEN);
    #pragma unroll
    for (int it = 0; it < 4; ++it) {
        const int col = it * 256 + lane * 4;
        float4 v = make_float4(0.f, 0.f, 0.f, 0.f);
        const int dd = l - col;
        if (dd >= 0 && dd < 4) ((float*)&v)[dd] = p0;
        if (l >= D) {
            const int dp = (l - D) - col;
            if (dp >= 0 && dp < 4) ((float*)&v)[dp] = p1;
        }
        arow[it * 64 + lane] = v;
    }
}

// o = out[:,PAST:] @ W^T + b, reshaped (B,1008,4,64) + residual inp[:,PAST:,:64]
// 16 rows per block staged in LDS; thread t owns output column c=t.
__global__ __launch_bounds__(256) void proj_kernel(const float* __restrict__ outbuf,
                                                   const float* __restrict__ inp,
                                                   const float* __restrict__ W,
                                                   const float* __restrict__ bias,
                                                   float* __restrict__ o)
{
    __shared__ float rows[16][DIM_IN];
    const int bid = blockIdx.x;
    const int b   = bid / 63;          // 63 blocks per batch (63*16 = 1008)
    const int lo0 = (bid % 63) * 16;
    const int t   = threadIdx.x;

    const float4* src = (const float4*)(outbuf + (size_t)(b * LEN + PAST + lo0) * DIM_IN);
    float4* dst = (float4*)rows;
    #pragma unroll
    for (int j = 0; j < 4; ++j) dst[t + 256 * j] = src[t + 256 * j];
    __syncthreads();

    const int c = t;
    float acc[16];
    #pragma unroll
    for (int r2 = 0; r2 < 16; ++r2) acc[r2] = 0.f;

    const float4* W4    = (const float4*)(W + (size_t)c * DIM_IN);
    const float4* rows4 = (const float4*)rows;
    for (int kq = 0; kq < 64; ++kq) {
        float4 wv = W4[kq];
        #pragma unroll
        for (int r2 = 0; r2 < 16; ++r2) {
            float4 xr = rows4[r2 * 64 + kq];  // same addr across wave -> broadcast
            acc[r2] += wv.x * xr.x + wv.y * xr.y + wv.z * xr.z + wv.w * xr.w;
        }
    }

    const float bv   = bias[c];
    const int   dcol = c & 63;
    #pragma unroll
    for (int r2 = 0; r2 < 16; ++r2) {
        const int lo = lo0 + r2;
        const float res = inp[(size_t)(b * LEN + PAST + lo) * DIM_IN + dcol];
        o[(size_t)(b * OUTROWS + lo) * 256 + c] = acc[r2] + bv + res;
    }
}

extern "C" void kernel_launch(void* const* d_in, const int* in_sizes, int n_in,
                              void* d_out, int out_size, void* d_ws, size_t ws_size,
                              hipStream_t stream) {
    const float* inp   = (const float*)d_in[0];
    const float* W_out = (const float*)d_in[1];
    const float* b_out = (const float*)d_in[2];
    // d_in[3] = masks: structure is known statically (diff in {0, d}), unused.

    float* o_out     = (float*)d_out;            // (B, 1008, 4, 64)
    float* attn_out  = o_out + O_ELEMS;          // (B, 3, 1024, 1024)

    float* buf0 = (float*)d_ws;                          // B*L*256 floats = 16 MB
    float* buf1 = buf0 + (size_t)BATCH * LEN * DIM_IN;   // second 16 MB

    const int nblk = BATCH * LEN / 4;  // one wave per row, 4 waves per block
    layer_kernel<1, 0><<<nblk, 256, 0, stream>>>(inp,  buf0, attn_out);
    layer_kernel<2, 1><<<nblk, 256, 0, stream>>>(buf0, buf1, attn_out);
    layer_kernel<4, 2><<<nblk, 256, 0, stream>>>(buf1, buf0, attn_out);

    proj_kernel<<<BATCH * 63, 256, 0, stream>>>(buf0, inp, W_out, b_out, o_out);
}

// Round 6
// 303.558 us; speedup vs baseline: 1.2133x; 1.2133x over previous
//
#include <hip/hip_runtime.h>

#define BATCH 16
#define LEN 1024
#define DIN 256
#define PAST 16
#define OUTROWS (LEN - PAST)           /* 1008 */
#define NL 3
#define TROWS 32                       /* owned rows per block */
#define HALO 8                         /* 7 needed, 8 for symmetry */
#define NR (TROWS + HALO)              /* 40 buffer rows */
#define O_ELEMS ((size_t)BATCH * OUTROWS * 256)

typedef float f4_t __attribute__((ext_vector_type(4)));

// One layer over all NR LDS rows. Wave per row, 8 waves -> 5 iterations.
// Writes the 4KB attn row (zeros + 2 scatter values) for owned rows only.
__device__ __forceinline__ void layer_step(const float (*S)[DIN], float (*D)[DIN],
                                           const int DD, const int layer,
                                           const int b, const int l0,
                                           const int wave, const int lane,
                                           float* __restrict__ attn)
{
    #pragma unroll
    for (int it = 0; it < NR / 8; ++it) {
        const int row = it * 8 + wave;            // 0..39 LDS row
        const int l   = l0 - HALO + row;          // global row (may be <0 in halo)
        const int ry  = (row >= DD) ? (row - DD) : 0;  // clamp: value unused when p1==0

        const float4 x = ((const float4*)(S[row]))[lane];
        const float4 y = ((const float4*)(S[ry]))[lane];

        float d0 = x.x * x.x + x.y * x.y + x.z * x.z + x.w * x.w;
        float d1 = x.x * y.x + x.y * y.y + x.z * y.z + x.w * y.w;
        #pragma unroll
        for (int off = 32; off; off >>= 1) {
            d0 += __shfl_xor(d0, off, 64);
            d1 += __shfl_xor(d1, off, 64);
        }

        float p0 = 1.f, p1 = 0.f;
        if (l >= DD) {
            const float s0 = d0 * 0.0625f, s1 = d1 * 0.0625f;  // 1/sqrt(256)
            const float m  = fmaxf(s0, s1);
            const float e0 = expf(s0 - m), e1 = expf(s1 - m);
            const float inv = 1.f / (e0 + e1);
            p0 = e0 * inv;
            p1 = e1 * inv;
        }

        const float a0 = 1.f + p0;
        float4 nv;
        nv.x = fmaf(y.x, p1, x.x * a0);
        nv.y = fmaf(y.y, p1, x.y * a0);
        nv.z = fmaf(y.z, p1, x.z * a0);
        nv.w = fmaf(y.w, p1, x.w * a0);
        ((float4*)(D[row]))[lane] = nv;

        if (row >= HALO) {   // owned row -> write attn_stack[b, layer, l, :]
            float* arow = attn + (((size_t)(b * NL + layer)) * LEN + l) * (size_t)LEN;
            #pragma unroll
            for (int j = 0; j < 4; ++j) {
                const int col = j * 256 + lane * 4;
                float4 v = make_float4(0.f, 0.f, 0.f, 0.f);
                const int dd = l - col;
                if (dd >= 0 && dd < 4) ((float*)&v)[dd] = p0;
                if (l >= DD) {
                    const int dp = (l - DD) - col;
                    if (dp >= 0 && dp < 4) ((float*)&v)[dp] = p1;
                }
                __builtin_nontemporal_store(*(const f4_t*)&v,
                                            (f4_t*)arow + j * 64 + lane);
            }
        }
    }
}

__global__ __launch_bounds__(512, 4) void fused_kernel(const float* __restrict__ inp,
                                                       const float* __restrict__ W,
                                                       const float* __restrict__ bias,
                                                       float* __restrict__ o,
                                                       float* __restrict__ attn)
{
    __shared__ float A[NR][DIN];    // 40 KB
    __shared__ float Bb[NR][DIN];   // 40 KB  -> 80 KB total, 2 blocks/CU

    const int blk  = blockIdx.x;
    const int b    = blk >> 5;              // 32 chunks per batch
    const int l0   = (blk & 31) * TROWS;
    const int t    = threadIdx.x;
    const int wave = t >> 6;
    const int lane = t & 63;

    // Stage inp rows [l0-8, l0+32) (clamped at 0) into A. 2560 float4, 5 rounds.
    {
        float4* dst = (float4*)A;
        const size_t base = (size_t)b * LEN;
        #pragma unroll
        for (int i = 0; i < 5; ++i) {
            const int idx = i * 512 + t;
            const int row = idx >> 6;
            int g = l0 - HALO + row; if (g < 0) g = 0;
            dst[idx] = ((const float4*)(inp + (base + g) * DIN))[idx & 63];
        }
    }
    __syncthreads();

    layer_step(A,  Bb, 1, 0, b, l0, wave, lane, attn);
    __syncthreads();
    layer_step(Bb, A,  2, 1, b, l0, wave, lane, attn);
    __syncthreads();
    layer_step(A,  Bb, 4, 2, b, l0, wave, lane, attn);
    __syncthreads();

    // Projection from LDS (Bb rows 8..39): o = x @ W^T + bias, + residual.
    // thread t: column c = t&255, row-half = t>>8 (16 rows each).
    const int half = t >> 8;
    const int c    = t & 255;
    float acc[16];
    #pragma unroll
    for (int r = 0; r < 16; ++r) acc[r] = 0.f;

    const float4* W4 = (const float4*)(W + (size_t)c * DIN);
    const float4* R4 = (const float4*)(Bb[HALO + half * 16]);
    for (int kq = 0; kq < 64; ++kq) {
        const float4 wv = W4[kq];
        #pragma unroll
        for (int r = 0; r < 16; ++r) {
            const float4 xr = R4[r * 64 + kq];  // broadcast across wave
            acc[r] = fmaf(wv.x, xr.x, acc[r]);
            acc[r] = fmaf(wv.y, xr.y, acc[r]);
            acc[r] = fmaf(wv.z, xr.z, acc[r]);
            acc[r] = fmaf(wv.w, xr.w, acc[r]);
        }
    }

    const float bv   = bias[c];
    const int   dcol = c & 63;
    #pragma unroll
    for (int r = 0; r < 16; ++r) {
        const int l = l0 + half * 16 + r;
        if (l >= PAST) {
            const float res = inp[((size_t)b * LEN + l) * DIN + dcol];
            o[((size_t)b * OUTROWS + (l - PAST)) * 256 + c] = acc[r] + bv + res;
        }
    }
}

extern "C" void kernel_launch(void* const* d_in, const int* in_sizes, int n_in,
                              void* d_out, int out_size, void* d_ws, size_t ws_size,
                              hipStream_t stream) {
    const float* inp   = (const float*)d_in[0];
    const float* W_out = (const float*)d_in[1];
    const float* b_out = (const float*)d_in[2];
    // d_in[3] = masks: structure known statically (diff in {0, d}), unused.

    float* o_out    = (float*)d_out;       // (B, 1008, 4, 64)
    float* attn_out = o_out + O_ELEMS;     // (B, 3, 1024, 1024)

    fused_kernel<<<BATCH * (LEN / TROWS), 512, 0, stream>>>(inp, W_out, b_out,
                                                            o_out, attn_out);
}